// Round 5
// baseline (1148.307 us; speedup 1.0000x reference)
//
#include <hip/hip_runtime.h>

constexpr int TT = 512;    // timesteps
constexpr int BB = 256;    // batch
constexpr int HH = 128;    // hidden = embed
constexpr int VV = 32000;  // vocab
constexpr int MB = 16;     // batch rows per block (MFMA M tile)

typedef _Float16 h2 __attribute__((ext_vector_type(2)));
typedef _Float16 f16x4 __attribute__((ext_vector_type(4)));
typedef _Float16 f16x8 __attribute__((ext_vector_type(8)));
typedef float f32x4 __attribute__((ext_vector_type(4)));

struct __align__(16) H2x4 { h2 a, b, c, d; };

__device__ __forceinline__ h2 pkrtz(float a, float b) {
  return __builtin_bit_cast(h2, __builtin_amdgcn_cvt_pkrtz(a, b));
}
__device__ __forceinline__ float fsigmoid(float x) {
  return 1.f / (1.f + __expf(-x));
}
__device__ __forceinline__ float ftanh(float x) {
  return 1.f - 2.f / (__expf(2.f * x) + 1.f);
}

// 16 blocks x 512 threads (8 waves). Block owns batch rows [16*bx, 16*bx+16).
// Per step: gates[n=512][m=16] = W^T[n][k=256] @ comb[k][m] via
// mfma_f32_16x16x32_f16 with A = weight fragments resident in VGPRs
// (wave w: units [16w,16w+16) x 4 gates x 8 k-tiles = 32 frags = 128 regs),
// B = comb read from LDS in fragment-swizzled layout (1 ds_read_b128/k-tile).
// D layout: lane&15 = batch m, quad*4+r = unit row -> all 4 gates of unit u
// land in one lane: c-state in lane regs, in-lane activation/state update,
// h written back as one ds_write_b64 into the double-buffered comb.
// One __syncthreads per step.
__global__ __launch_bounds__(512, 2) void lstm_rec(
    const int* __restrict__ x, const float* __restrict__ emb,
    const float* __restrict__ Wi, const float* __restrict__ bi,
    const float* __restrict__ Wf, const float* __restrict__ bf,
    const float* __restrict__ Wc, const float* __restrict__ bc,
    const float* __restrict__ Wo, const float* __restrict__ bo,
    _Float16* __restrict__ hbf) {
  const int tid = threadIdx.x;
  const int w = tid >> 6;      // wave 0..7
  const int lane = tid & 63;
  const int m16 = lane & 15;   // A-load: unit offset; B/D: batch m
  const int quad = lane >> 4;
  const int B0 = blockIdx.x * MB;

  constexpr int BUFSZ = 8 * 512;                      // elements per buffer
  __shared__ __align__(16) _Float16 comb[2 * BUFSZ];  // [buf][ktile][lane*8+j]
  __shared__ int xt[MB][TT + 4];                      // +4 pad: bank spread

  // ---- stage x tile (16 rows x 512) ----
  {
    const int mm = tid >> 5;
    const int c16 = (tid & 31) * 16;
    const int4* src = (const int4*)(x + (size_t)(B0 + mm) * TT + c16);
    int4* dst = (int4*)(&xt[mm][c16]);
#pragma unroll
    for (int i = 0; i < 4; ++i) dst[i] = src[i];
  }

  // ---- weight fragments (A-operand): n = g*128 + 16w + m16, k = kt*32+quad*8+j
  const float* Wp[4] = {Wi, Wf, Wc, Wo};
  f16x8 wfrag[4][8];
  const int ncol = 16 * w + m16;
#pragma unroll
  for (int g = 0; g < 4; ++g) {
    const float* Wg = Wp[g];
#pragma unroll
    for (int kt = 0; kt < 8; ++kt) {
      const float* base = Wg + (size_t)(kt * 32 + quad * 8) * HH + ncol;
      f16x8 v;
#pragma unroll
      for (int j = 0; j < 8; ++j) v[j] = (_Float16)base[j * HH];
      wfrag[g][kt] = v;
    }
  }

  // biases for this thread's 4 units u = u0 + r
  const int u0 = 16 * w + 4 * quad;
  float bia[4], bif[4], bic[4], bio[4];
#pragma unroll
  for (int r = 0; r < 4; ++r) {
    bia[r] = bi[u0 + r]; bif[r] = bf[u0 + r];
    bic[r] = bc[u0 + r]; bio[r] = bo[u0 + r];
  }

  // e-prefetch mapping: thread covers e[m = tid&15][k = 4*g5 .. 4*g5+4)
  const int em = tid & 15;
  const int g5 = tid >> 4;                       // 0..31
  const int ekt = g5 >> 3;                       // k-tile 0..3
  const int elane = em + 16 * ((g5 >> 1) & 3);   // fragment lane
  const int eslot = 4 * (g5 & 1);                // f16 slot within 8
  const int ek = g5 * 4;
  const int eoff = ekt * 512 + elane * 8 + eslot;

  // h-write mapping: u = 16w + 4q + r -> k = 128+u:
  // kt = 4 + (w>>1), lane' = m16 + 16*(2*(w&1) + (q>>1)), j0 = 4*(q&1)
  const int hoff = (4 + (w >> 1)) * 512 +
                   (m16 + 16 * (2 * (w & 1) + (quad >> 1))) * 8 + 4 * (quad & 1);

  __syncthreads();  // xt visible

  // ---- init buf 0: h = 0 (kt 4..7), e_0 (kt 0..3) ----
  *(f16x4*)(&comb[(4 + (tid >> 7)) * 512 + (tid & 127) * 4]) = f16x4{0, 0, 0, 0};
  {
    const int tok = xt[em][0];
    const float4 e4 = *(const float4*)(emb + (size_t)tok * HH + ek);
    *(f16x4*)(&comb[eoff]) = f16x4{(_Float16)e4.x, (_Float16)e4.y,
                                   (_Float16)e4.z, (_Float16)e4.w};
  }
  __syncthreads();

  float cst[4] = {0.f, 0.f, 0.f, 0.f};
  int buf = 0;

  for (int t = 0; t < TT; ++t) {
    // B-fragments from comb[buf] (conflict-free contiguous b128)
    f16x8 bfrag[8];
    const _Float16* cb = &comb[buf * BUFSZ + lane * 8];
#pragma unroll
    for (int kt = 0; kt < 8; ++kt) bfrag[kt] = *(const f16x8*)(cb + kt * 512);

    // issue e_{t+1} global load early (L2/L3-resident emb rows)
    const int tn = (t + 1 < TT) ? t + 1 : TT - 1;
    const int tok = xt[em][tn];
    const float4 e4 = *(const float4*)(emb + (size_t)tok * HH + ek);

    // 32 MFMA: 4 gates x 8 k-tiles
    f32x4 acc[4] = {{0, 0, 0, 0}, {0, 0, 0, 0}, {0, 0, 0, 0}, {0, 0, 0, 0}};
#pragma unroll
    for (int kt = 0; kt < 8; ++kt) {
#pragma unroll
      for (int g = 0; g < 4; ++g)
        acc[g] = __builtin_amdgcn_mfma_f32_16x16x32_f16(wfrag[g][kt], bfrag[kt],
                                                        acc[g], 0, 0, 0);
    }

    // in-lane activation + state update for units u0..u0+3, batch m16
    f16x4 hv;
#pragma unroll
    for (int r = 0; r < 4; ++r) {
      const float gi = fsigmoid(acc[0][r] + bia[r]);
      const float gf = fsigmoid(acc[1][r] + bif[r]);
      const float gc = ftanh(acc[2][r] + bic[r]);
      const float go = fsigmoid(acc[3][r] + bio[r]);
      cst[r] = gf * cst[r] + gi * gc;
      hv[r] = (_Float16)(go * ftanh(cst[r]));
    }

    // h and e_{t+1} into the other buffer
    const int nbuf = (buf ^ 1) * BUFSZ;
    *(f16x4*)(&comb[nbuf + hoff]) = hv;
    *(f16x4*)(&comb[nbuf + eoff]) = f16x4{(_Float16)e4.x, (_Float16)e4.y,
                                          (_Float16)e4.z, (_Float16)e4.w};

    if (t == TT - 1)
      *(f16x4*)(hbf + (size_t)(B0 + m16) * HH + u0) = hv;

    __syncthreads();
    buf ^= 1;
  }
}

// Wout[k][v] fp32 -> Wt[v][k] fp16 (coalesced loads across lanes=v).
__global__ __launch_bounds__(256, 4) void wout_tr(const float* __restrict__ Wout,
                                                  _Float16* __restrict__ Wt) {
  const int v = blockIdx.x * 256 + threadIdx.x;
#pragma unroll 1
  for (int kc = 0; kc < 16; ++kc) {
    float f[8];
#pragma unroll
    for (int i = 0; i < 8; ++i) f[i] = Wout[(size_t)(kc * 8 + i) * VV + v];
    H2x4 q;
    q.a = pkrtz(f[0], f[1]);
    q.b = pkrtz(f[2], f[3]);
    q.c = pkrtz(f[4], f[5]);
    q.d = pkrtz(f[6], f[7]);
    *(H2x4*)(Wt + (size_t)v * HH + kc * 8) = q;
  }
}

// logits = h @ Wout + bout via f16 MFMA, register-only.
// Block: 4 waves; tile [64 bat x 128 v]; wave: [64 bat x 32 v].
__global__ __launch_bounds__(256, 4) void lstm_out(
    const _Float16* __restrict__ Wt, const _Float16* __restrict__ hbf,
    const float* __restrict__ bout, float* __restrict__ out) {
  const int tid = threadIdx.x;
  const int wv = tid >> 6;
  const int lane = tid & 63;
  const int vblk = blockIdx.x % 250;
  const int batblk = blockIdx.x / 250;
  const int n16 = lane & 15;
  const int quad = lane >> 4;
  const int vbase = vblk * 128 + wv * 32;
  const int batbase = batblk * 64;

  f32x4 acc[4][2] = {};
#pragma unroll
  for (int ks = 0; ks < 4; ++ks) {
    const int k = ks * 32 + quad * 8;
    f16x8 a[4], bf_[2];
#pragma unroll
    for (int mt = 0; mt < 4; ++mt)
      a[mt] = *(const f16x8*)(hbf + (size_t)(batbase + mt * 16 + n16) * HH + k);
#pragma unroll
    for (int vt = 0; vt < 2; ++vt)
      bf_[vt] = *(const f16x8*)(Wt + (size_t)(vbase + vt * 16 + n16) * HH + k);
#pragma unroll
    for (int mt = 0; mt < 4; ++mt)
#pragma unroll
      for (int vt = 0; vt < 2; ++vt)
        acc[mt][vt] = __builtin_amdgcn_mfma_f32_16x16x32_f16(a[mt], bf_[vt],
                                                             acc[mt][vt], 0, 0, 0);
  }
#pragma unroll
  for (int vt = 0; vt < 2; ++vt) {
    const int v = vbase + vt * 16 + n16;
    const float bv = bout[v];
#pragma unroll
    for (int mt = 0; mt < 4; ++mt) {
#pragma unroll
      for (int r = 0; r < 4; ++r) {
        const int bat = batbase + mt * 16 + quad * 4 + r;
        out[(size_t)bat * VV + v] = acc[mt][vt][r] + bv;
      }
    }
  }
}

extern "C" void kernel_launch(void* const* d_in, const int* in_sizes, int n_in,
                              void* d_out, int out_size, void* d_ws,
                              size_t ws_size, hipStream_t stream) {
  const int* x = (const int*)d_in[0];
  const float* emb = (const float*)d_in[1];
  const float* Wi = (const float*)d_in[2];
  const float* bi = (const float*)d_in[3];
  const float* Wf = (const float*)d_in[4];
  const float* bf = (const float*)d_in[5];
  const float* Wc = (const float*)d_in[6];
  const float* bc = (const float*)d_in[7];
  const float* Wo = (const float*)d_in[8];
  const float* bo = (const float*)d_in[9];
  const float* Wout = (const float*)d_in[10];
  const float* bout = (const float*)d_in[11];
  float* out = (float*)d_out;

  _Float16* Wt = (_Float16*)d_ws;        // 32000*128 fp16 = 8.192 MB
  _Float16* hbf = Wt + (size_t)VV * HH;  // 256*128 fp16 = 64 KB

  wout_tr<<<VV / 256, 256, 0, stream>>>(Wout, Wt);
  lstm_rec<<<BB / MB, 512, 0, stream>>>(x, emb, Wi, bi, Wf, bf, Wc, bc, Wo, bo,
                                        hbf);
  lstm_out<<<(VV / 128) * (BB / 64), 256, 0, stream>>>(Wt, hbf, bout, out);
}